// Round 2
// baseline (778.283 us; speedup 1.0000x reference)
//
#include <hip/hip_runtime.h>

#define N_TOK 4096
#define DM 256
#define NH 8
#define DK 32
#define QT 16      // queries per attn block
#define CH 128     // K/V rows staged per LDS chunk

using u16 = unsigned short;
using u32 = unsigned int;
using i64 = long long;
typedef float f32x4 __attribute__((ext_vector_type(4)));

__device__ __forceinline__ float bfl(u32 u){ return __uint_as_float(u << 16); }          // low bf16 of a u32
__device__ __forceinline__ float bfh(u32 u){ return __uint_as_float(u & 0xffff0000u); }  // high bf16
__device__ __forceinline__ u16 f2bf(float f){
    u32 x = __float_as_uint(f);
    x += 0x7fffu + ((x >> 16) & 1u);
    return (u16)(x >> 16);
}

// ---- per-query segment bounds (batch sorted; int32 or int64 probed) ----
__global__ __launch_bounds__(256)
void bounds_kernel(const void* __restrict__ batch_q, const void* __restrict__ batch_kv,
                   int2* __restrict__ bounds)
{
    int q = blockIdx.x * 256 + threadIdx.x;
    const int* kv32 = (const int*)batch_kv;
    const i64* kv64 = (const i64*)batch_kv;
    bool is64 = (kv32[N_TOK - 1] == 0);
    int s = is64 ? (int)((const i64*)batch_q)[q] : ((const int*)batch_q)[q];
    int lo = 0, hi = N_TOK;
    while (lo < hi){ int m = (lo + hi) >> 1; int v = is64 ? (int)kv64[m] : kv32[m]; if (v < s) lo = m + 1; else hi = m; }
    int lo2 = lo, hi2 = N_TOK;
    while (lo2 < hi2){ int m = (lo2 + hi2) >> 1; int v = is64 ? (int)kv64[m] : kv32[m]; if (v <= s) lo2 = m + 1; else hi2 = m; }
    bounds[q] = make_int2(lo, lo2);
}

// out[r][c] = sum_d x[r][d] * W[c][d] + b[c]
template<int OUT_BF16>
__global__ __launch_bounds__(256)
void proj_kernel(const float* __restrict__ x, const float* __restrict__ W,
                 const float* __restrict__ bias, void* __restrict__ outv)
{
    const int ROWS = 16;
    int row0 = blockIdx.x * ROWS;
    int c = threadIdx.x;
    float acc[ROWS];
    float bv = bias[c];
#pragma unroll
    for (int r = 0; r < ROWS; ++r) acc[r] = bv;
    const float4* Wv = (const float4*)(W + (size_t)c * DM);
    for (int i = 0; i < DM / 4; ++i){
        float4 w = Wv[i];
        int d0 = i * 4;
#pragma unroll
        for (int r = 0; r < ROWS; ++r){
            const float* xr = x + (size_t)(row0 + r) * DM + d0;
            acc[r] += xr[0] * w.x + xr[1] * w.y + xr[2] * w.z + xr[3] * w.w;
        }
    }
#pragma unroll
    for (int r = 0; r < ROWS; ++r){
        size_t idx = (size_t)(row0 + r) * DM + c;
        if (OUT_BF16) ((u16*)outv)[idx] = f2bf(acc[r]);
        else          ((float*)outv)[idx] = acc[r];
    }
}

// Fused K+V projection; writes bf16 K,V in HEAD-MAJOR layout [h][token][32]
__global__ __launch_bounds__(256)
void proj_kv_kernel(const float* __restrict__ x, const float* __restrict__ Wk,
                    const float* __restrict__ bk, const float* __restrict__ Wv,
                    const float* __restrict__ bv, u16* __restrict__ Kp,
                    u16* __restrict__ Vp)
{
    const int ROWS = 16;
    int row0 = blockIdx.x * ROWS;
    int c = threadIdx.x;
    int hh = c >> 5, dd = c & 31;
    float acck[ROWS], accv[ROWS];
    float bkv = bk[c], bvv = bv[c];
#pragma unroll
    for (int r = 0; r < ROWS; ++r){ acck[r] = bkv; accv[r] = bvv; }
    const float4* Wk4 = (const float4*)(Wk + (size_t)c * DM);
    const float4* Wv4 = (const float4*)(Wv + (size_t)c * DM);
    for (int i = 0; i < DM / 4; ++i){
        float4 wk = Wk4[i];
        float4 wv = Wv4[i];
        int d0 = i * 4;
#pragma unroll
        for (int r = 0; r < ROWS; ++r){
            const float* xr = x + (size_t)(row0 + r) * DM + d0;
            float x0 = xr[0], x1 = xr[1], x2 = xr[2], x3 = xr[3];
            acck[r] += x0 * wk.x + x1 * wk.y + x2 * wk.z + x3 * wk.w;
            accv[r] += x0 * wv.x + x1 * wv.y + x2 * wv.z + x3 * wv.w;
        }
    }
#pragma unroll
    for (int r = 0; r < ROWS; ++r){
        size_t idx = ((size_t)hh * N_TOK + (row0 + r)) * DK + dd;
        Kp[idx] = f2bf(acck[r]);
        Vp[idx] = f2bf(accv[r]);
    }
}

// Stream zeros over the whole attn buffer at fill rate (zeros = 15/16 of it).
__global__ __launch_bounds__(256)
void zero_kernel(f32x4* __restrict__ p, int n4)
{
    int i = blockIdx.x * 256 + threadIdx.x;
    int stride = gridDim.x * 256;
    f32x4 z = {0.f, 0.f, 0.f, 0.f};
    for (; i < n4; i += stride) __builtin_nontemporal_store(z, &p[i]);
}

// One block per (head, 16-query tile). Two-pass flash softmax:
//   P1: online (m,s) per row, K chunks staged in LDS (16x reuse).
//   P2: recompute dot, write in-span probs only, accumulate PV in registers.
__global__ __launch_bounds__(256)
void attn_kernel(const float* __restrict__ Q, const u16* __restrict__ K,
                 const u16* __restrict__ V, const int2* __restrict__ bounds,
                 float* __restrict__ attn, float* __restrict__ O)
{
    __shared__ uint4 kch[CH][5];   // pad to 80B stride: 2-way LDS aliasing only (free)
    __shared__ uint4 vch[CH][5];

    const int tid = threadIdx.x;
    const int ql  = tid >> 4;          // query row within tile (0..15)
    const int kk  = tid & 15;          // k lane within the 16-lane row group
    const int h   = blockIdx.y;
    const int q0  = blockIdx.x * QT;
    const int q   = q0 + ql;

    const int2 bq = bounds[q];
    const int lo = bq.x, hi = bq.y;
    const int lo_min = bounds[q0].x;            // batch sorted -> tile span
    const int hi_max = bounds[q0 + QT - 1].y;

    const u16* Kh = K + (size_t)h * N_TOK * DK;
    const u16* Vh = V + (size_t)h * N_TOK * DK;

    // Q row (fp32) in registers
    float qr[32];
    {
        const float4* qp = (const float4*)(Q + (size_t)q * DM + h * DK);
#pragma unroll
        for (int i = 0; i < 8; ++i){
            float4 t = qp[i];
            qr[4*i+0] = t.x; qr[4*i+1] = t.y; qr[4*i+2] = t.z; qr[4*i+3] = t.w;
        }
    }

    const float scale = 0.17677669529663687f;   // 1/sqrt(32)

    // ---------- pass 1: online (max, sum) ----------
    float m = -1e30f, s = 0.f;
    for (int kc = lo_min; kc < hi_max; kc += CH){
        __syncthreads();
        for (int e = tid; e < CH * 4; e += 256){
            int r = e >> 2, p = e & 3;
            if (kc + r < hi_max)
                kch[r][p] = *(const uint4*)(Kh + (size_t)(kc + r) * DK + p * 8);
        }
        __syncthreads();
        int kend = min(CH, hi_max - kc);
        for (int j = kk; j < kend; j += 16){
            int k = kc + j;
            if (k < lo || k >= hi) continue;
            float dot = 0.f;
#pragma unroll
            for (int p = 0; p < 4; ++p){
                uint4 a = kch[j][p];
                dot += qr[8*p+0]*bfl(a.x) + qr[8*p+1]*bfh(a.x);
                dot += qr[8*p+2]*bfl(a.y) + qr[8*p+3]*bfh(a.y);
                dot += qr[8*p+4]*bfl(a.z) + qr[8*p+5]*bfh(a.z);
                dot += qr[8*p+6]*bfl(a.w) + qr[8*p+7]*bfh(a.w);
            }
            float d = dot * scale;
            float mn = fmaxf(m, d);
            s = s * __expf(m - mn) + __expf(d - mn);
            m = mn;
        }
    }
    // reduce (m,s) across the 16 k-lanes of each row group
#pragma unroll
    for (int off = 1; off < 16; off <<= 1){
        float mo = __shfl_xor(m, off, 64);
        float so = __shfl_xor(s, off, 64);
        float mn = fmaxf(m, mo);
        s = s * __expf(m - mn) + so * __expf(mo - mn);
        m = mn;
    }
    const float inv = (s > 0.f) ? 1.0f / s : 0.f;

    // ---------- pass 2: write probs + PV ----------
    float o[32];
#pragma unroll
    for (int d = 0; d < 32; ++d) o[d] = 0.f;

    float* arow = attn + ((size_t)h * N_TOK + q) * N_TOK;

    for (int kc = lo_min; kc < hi_max; kc += CH){
        __syncthreads();
        for (int e = tid; e < CH * 4; e += 256){
            int r = e >> 2, p = e & 3;
            if (kc + r < hi_max){
                kch[r][p] = *(const uint4*)(Kh + (size_t)(kc + r) * DK + p * 8);
                vch[r][p] = *(const uint4*)(Vh + (size_t)(kc + r) * DK + p * 8);
            }
        }
        __syncthreads();
        int kend = min(CH, hi_max - kc);
        for (int j = kk; j < kend; j += 16){
            int k = kc + j;
            if (k < lo || k >= hi) continue;
            float dot = 0.f;
#pragma unroll
            for (int p = 0; p < 4; ++p){
                uint4 a = kch[j][p];
                dot += qr[8*p+0]*bfl(a.x) + qr[8*p+1]*bfh(a.x);
                dot += qr[8*p+2]*bfl(a.y) + qr[8*p+3]*bfh(a.y);
                dot += qr[8*p+4]*bfl(a.z) + qr[8*p+5]*bfh(a.z);
                dot += qr[8*p+6]*bfl(a.w) + qr[8*p+7]*bfh(a.w);
            }
            float pr = __expf(dot * scale - m) * inv;
            __builtin_nontemporal_store(pr, &arow[k]);
#pragma unroll
            for (int pp = 0; pp < 4; ++pp){
                uint4 a = vch[j][pp];
                o[8*pp+0] += pr * bfl(a.x); o[8*pp+1] += pr * bfh(a.x);
                o[8*pp+2] += pr * bfl(a.y); o[8*pp+3] += pr * bfh(a.y);
                o[8*pp+4] += pr * bfl(a.z); o[8*pp+5] += pr * bfh(a.z);
                o[8*pp+6] += pr * bfl(a.w); o[8*pp+7] += pr * bfh(a.w);
            }
        }
    }

    // butterfly-reduce o[] across the 16 k-lanes (all lanes end with row sums)
#pragma unroll
    for (int d = 0; d < 32; ++d){
#pragma unroll
        for (int off = 1; off < 16; off <<= 1)
            o[d] += __shfl_xor(o[d], off, 64);
    }
    // lane kk stores dims (2kk, 2kk+1); static-index extraction (no scratch)
    float s0 = 0.f, s1 = 0.f;
#pragma unroll
    for (int d = 0; d < 16; ++d)
        if (kk == d){ s0 = o[2*d]; s1 = o[2*d + 1]; }
    *(float2*)(O + (size_t)q * DM + h * DK + 2 * kk) = make_float2(s0, s1);
}

extern "C" void kernel_launch(void* const* d_in, const int* in_sizes, int n_in,
                              void* d_out, int out_size, void* d_ws, size_t ws_size,
                              hipStream_t stream)
{
    const float* x_q  = (const float*)d_in[0];
    const float* x_kv = (const float*)d_in[1];
    const void* batch_q  = d_in[2];
    const void* batch_kv = d_in[3];
    const float* Wq = (const float*)d_in[4];
    const float* bq = (const float*)d_in[5];
    const float* Wk = (const float*)d_in[6];
    const float* bk = (const float*)d_in[7];
    const float* Wv = (const float*)d_in[8];
    const float* bv = (const float*)d_in[9];
    const float* Wo = (const float*)d_in[10];
    const float* bo = (const float*)d_in[11];

    char* ws = (char*)d_ws;
    float* Q  = (float*)ws;                                 // 4 MB fp32
    u16*   Kp = (u16*)(ws + (size_t)4 * 1024 * 1024);       // 2 MB bf16, head-major
    u16*   Vp = (u16*)(ws + (size_t)6 * 1024 * 1024);       // 2 MB bf16, head-major
    float* O  = (float*)(ws + (size_t)8 * 1024 * 1024);     // 4 MB fp32
    int2* bounds = (int2*)(ws + (size_t)12 * 1024 * 1024);  // 32 KB

    float* out  = (float*)d_out;                            // [4096,256] fp32
    float* attn = out + (size_t)N_TOK * DM;                 // [8,4096,4096] fp32

    // stream zeros first (covers the 15/16 masked-out region at fill rate)
    int n4 = (int)((size_t)NH * N_TOK * N_TOK / 4);
    zero_kernel<<<2048, 256, 0, stream>>>((f32x4*)attn, n4);

    bounds_kernel<<<N_TOK / 256, 256, 0, stream>>>(batch_q, batch_kv, bounds);
    proj_kernel<0><<<N_TOK/16, 256, 0, stream>>>(x_q,  Wq, bq, Q);
    proj_kv_kernel<<<N_TOK/16, 256, 0, stream>>>(x_kv, Wk, bk, Wv, bv, Kp, Vp);
    attn_kernel<<<dim3(N_TOK / QT, NH), 256, 0, stream>>>(Q, Kp, Vp, bounds, attn, O);
    proj_kernel<0><<<N_TOK/16, 256, 0, stream>>>((const float*)O, Wo, bo, out);
}

// Round 3
// 744.736 us; speedup vs baseline: 1.0450x; 1.0450x over previous
//
#include <hip/hip_runtime.h>

#define N_TOK 4096
#define DM 256
#define NH 8
#define DK 32
#define QT 16      // queries per attn block
#define CH 128     // K/V rows staged per LDS chunk

using u16 = unsigned short;
using u32 = unsigned int;
using i64 = long long;
typedef float f32x4 __attribute__((ext_vector_type(4)));

__device__ __forceinline__ float bfl(u32 u){ return __uint_as_float(u << 16); }          // low bf16 of a u32
__device__ __forceinline__ float bfh(u32 u){ return __uint_as_float(u & 0xffff0000u); }  // high bf16
__device__ __forceinline__ u16 f2bf(float f){
    u32 x = __float_as_uint(f);
    x += 0x7fffu + ((x >> 16) & 1u);
    return (u16)(x >> 16);
}

// ---- per-query segment bounds (batch sorted; int32 or int64 probed) ----
__global__ __launch_bounds__(256)
void bounds_kernel(const void* __restrict__ batch_q, const void* __restrict__ batch_kv,
                   int2* __restrict__ bounds)
{
    int q = blockIdx.x * 256 + threadIdx.x;
    const int* kv32 = (const int*)batch_kv;
    const i64* kv64 = (const i64*)batch_kv;
    bool is64 = (kv32[N_TOK - 1] == 0);
    int s = is64 ? (int)((const i64*)batch_q)[q] : ((const int*)batch_q)[q];
    int lo = 0, hi = N_TOK;
    while (lo < hi){ int m = (lo + hi) >> 1; int v = is64 ? (int)kv64[m] : kv32[m]; if (v < s) lo = m + 1; else hi = m; }
    int lo2 = lo, hi2 = N_TOK;
    while (lo2 < hi2){ int m = (lo2 + hi2) >> 1; int v = is64 ? (int)kv64[m] : kv32[m]; if (v <= s) lo2 = m + 1; else hi2 = m; }
    bounds[q] = make_int2(lo, lo2);
}

// out[r][c] = sum_d x[r][d] * W[c][d] + b[c]
// ROWS=8 -> 512 blocks (2/CU, 2 waves/SIMD) for latency hiding; float4 x loads.
template<int OUT_BF16>
__global__ __launch_bounds__(256)
void proj_kernel(const float* __restrict__ x, const float* __restrict__ W,
                 const float* __restrict__ bias, void* __restrict__ outv)
{
    const int ROWS = 8;
    int row0 = blockIdx.x * ROWS;
    int c = threadIdx.x;
    float acc[ROWS];
    float bv = bias[c];
#pragma unroll
    for (int r = 0; r < ROWS; ++r) acc[r] = bv;
    const float4* Wv = (const float4*)(W + (size_t)c * DM);
    const float4* xb = (const float4*)(x + (size_t)row0 * DM);
    for (int i = 0; i < DM / 4; ++i){
        float4 w = Wv[i];
#pragma unroll
        for (int r = 0; r < ROWS; ++r){
            float4 xv = xb[r * (DM / 4) + i];
            acc[r] += xv.x * w.x + xv.y * w.y + xv.z * w.z + xv.w * w.w;
        }
    }
#pragma unroll
    for (int r = 0; r < ROWS; ++r){
        size_t idx = (size_t)(row0 + r) * DM + c;
        if (OUT_BF16) ((u16*)outv)[idx] = f2bf(acc[r]);
        else          ((float*)outv)[idx] = acc[r];
    }
}

// Fused K+V projection; writes bf16 K,V in HEAD-MAJOR layout [h][token][32]
__global__ __launch_bounds__(256)
void proj_kv_kernel(const float* __restrict__ x, const float* __restrict__ Wk,
                    const float* __restrict__ bk, const float* __restrict__ Wv,
                    const float* __restrict__ bv, u16* __restrict__ Kp,
                    u16* __restrict__ Vp)
{
    const int ROWS = 8;
    int row0 = blockIdx.x * ROWS;
    int c = threadIdx.x;
    int hh = c >> 5, dd = c & 31;
    float acck[ROWS], accv[ROWS];
    float bkv = bk[c], bvv = bv[c];
#pragma unroll
    for (int r = 0; r < ROWS; ++r){ acck[r] = bkv; accv[r] = bvv; }
    const float4* Wk4 = (const float4*)(Wk + (size_t)c * DM);
    const float4* Wv4 = (const float4*)(Wv + (size_t)c * DM);
    const float4* xb  = (const float4*)(x + (size_t)row0 * DM);
    for (int i = 0; i < DM / 4; ++i){
        float4 wk = Wk4[i];
        float4 wv = Wv4[i];
#pragma unroll
        for (int r = 0; r < ROWS; ++r){
            float4 xv = xb[r * (DM / 4) + i];
            acck[r] += xv.x * wk.x + xv.y * wk.y + xv.z * wk.z + xv.w * wk.w;
            accv[r] += xv.x * wv.x + xv.y * wv.y + xv.z * wv.z + xv.w * wv.w;
        }
    }
#pragma unroll
    for (int r = 0; r < ROWS; ++r){
        size_t idx = ((size_t)hh * N_TOK + (row0 + r)) * DK + dd;
        Kp[idx] = f2bf(acck[r]);
        Vp[idx] = f2bf(accv[r]);
    }
}

// One block per (head, 16-query tile). Two-pass flash softmax.
// This kernel now ALSO writes the zero regions of its 16 attn rows (tail sweep),
// so the full 512MB attn output comes from here and overlaps with compute.
__global__ __launch_bounds__(256)
void attn_kernel(const float* __restrict__ Q, const u16* __restrict__ K,
                 const u16* __restrict__ V, const int2* __restrict__ bounds,
                 float* __restrict__ attn, float* __restrict__ O)
{
    __shared__ uint4 kch[CH][5];   // pad to 80B stride: 2-way LDS aliasing only (free)
    __shared__ uint4 vch[CH][5];

    const int tid = threadIdx.x;
    const int ql  = tid >> 4;          // query row within tile (0..15)
    const int kk  = tid & 15;          // k lane within the 16-lane row group
    const int h   = blockIdx.y;
    const int q0  = blockIdx.x * QT;
    const int q   = q0 + ql;

    const int2 bq = bounds[q];
    const int lo = bq.x, hi = bq.y;
    const int lo_min = bounds[q0].x;            // batch sorted -> tile span
    const int hi_max = bounds[q0 + QT - 1].y;

    const u16* Kh = K + (size_t)h * N_TOK * DK;
    const u16* Vh = V + (size_t)h * N_TOK * DK;

    // Q row (fp32) in registers
    float qr[32];
    {
        const float4* qp = (const float4*)(Q + (size_t)q * DM + h * DK);
#pragma unroll
        for (int i = 0; i < 8; ++i){
            float4 t = qp[i];
            qr[4*i+0] = t.x; qr[4*i+1] = t.y; qr[4*i+2] = t.z; qr[4*i+3] = t.w;
        }
    }

    const float scale = 0.17677669529663687f;   // 1/sqrt(32)

    // ---------- pass 1: online (max, sum), one exp on the common path ----------
    float m = -1e30f, s = 0.f;
    for (int kc = lo_min; kc < hi_max; kc += CH){
        __syncthreads();
        for (int e = tid; e < CH * 4; e += 256){
            int r = e >> 2, p = e & 3;
            if (kc + r < hi_max)
                kch[r][p] = *(const uint4*)(Kh + (size_t)(kc + r) * DK + p * 8);
        }
        __syncthreads();
        int kend = min(CH, hi_max - kc);
        for (int j = kk; j < kend; j += 16){
            int k = kc + j;
            if (k < lo || k >= hi) continue;
            float dot = 0.f;
#pragma unroll
            for (int p = 0; p < 4; ++p){
                uint4 a = kch[j][p];
                dot += qr[8*p+0]*bfl(a.x) + qr[8*p+1]*bfh(a.x);
                dot += qr[8*p+2]*bfl(a.y) + qr[8*p+3]*bfh(a.y);
                dot += qr[8*p+4]*bfl(a.z) + qr[8*p+5]*bfh(a.z);
                dot += qr[8*p+6]*bfl(a.w) + qr[8*p+7]*bfh(a.w);
            }
            float d = dot * scale;
            if (d <= m){
                s += __expf(d - m);
            } else {
                s = s * __expf(m - d) + 1.f;
                m = d;
            }
        }
    }
    // reduce (m,s) across the 16 k-lanes of each row group
#pragma unroll
    for (int off = 1; off < 16; off <<= 1){
        float mo = __shfl_xor(m, off, 64);
        float so = __shfl_xor(s, off, 64);
        float mn = fmaxf(m, mo);
        s = s * __expf(m - mn) + so * __expf(mo - mn);
        m = mn;
    }
    const float inv = (s > 0.f) ? 1.0f / s : 0.f;

    // ---------- pass 2: write in-span probs + PV ----------
    float o[32];
#pragma unroll
    for (int d = 0; d < 32; ++d) o[d] = 0.f;

    float* arow = attn + ((size_t)h * N_TOK + q) * N_TOK;

    for (int kc = lo_min; kc < hi_max; kc += CH){
        __syncthreads();
        for (int e = tid; e < CH * 4; e += 256){
            int r = e >> 2, p = e & 3;
            if (kc + r < hi_max){
                kch[r][p] = *(const uint4*)(Kh + (size_t)(kc + r) * DK + p * 8);
                vch[r][p] = *(const uint4*)(Vh + (size_t)(kc + r) * DK + p * 8);
            }
        }
        __syncthreads();
        int kend = min(CH, hi_max - kc);
        for (int j = kk; j < kend; j += 16){
            int k = kc + j;
            if (k < lo || k >= hi) continue;
            float dot = 0.f;
#pragma unroll
            for (int p = 0; p < 4; ++p){
                uint4 a = kch[j][p];
                dot += qr[8*p+0]*bfl(a.x) + qr[8*p+1]*bfh(a.x);
                dot += qr[8*p+2]*bfl(a.y) + qr[8*p+3]*bfh(a.y);
                dot += qr[8*p+4]*bfl(a.z) + qr[8*p+5]*bfh(a.z);
                dot += qr[8*p+6]*bfl(a.w) + qr[8*p+7]*bfh(a.w);
            }
            float pr = __expf(dot * scale - m) * inv;
            __builtin_nontemporal_store(pr, &arow[k]);
#pragma unroll
            for (int pp = 0; pp < 4; ++pp){
                uint4 a = vch[j][pp];
                o[8*pp+0] += pr * bfl(a.x); o[8*pp+1] += pr * bfh(a.x);
                o[8*pp+2] += pr * bfl(a.y); o[8*pp+3] += pr * bfh(a.y);
                o[8*pp+4] += pr * bfl(a.z); o[8*pp+5] += pr * bfh(a.z);
                o[8*pp+6] += pr * bfl(a.w); o[8*pp+7] += pr * bfh(a.w);
            }
        }
    }

    // butterfly-reduce o[] across the 16 k-lanes (all lanes end with row sums)
#pragma unroll
    for (int d = 0; d < 32; ++d){
#pragma unroll
        for (int off = 1; off < 16; off <<= 1)
            o[d] += __shfl_xor(o[d], off, 64);
    }
    // lane kk stores dims (2kk, 2kk+1); static-index extraction (no scratch)
    float s0 = 0.f, s1 = 0.f;
#pragma unroll
    for (int d = 0; d < 16; ++d)
        if (kk == d){ s0 = o[2*d]; s1 = o[2*d + 1]; }
    *(float2*)(O + (size_t)q * DM + h * DK + 2 * kk) = make_float2(s0, s1);

    // ---------- tail: zero the out-of-segment regions of this tile's 16 rows ----
    // Disjoint from the prob stores above -> no sync needed; drain overlaps
    // other resident blocks' compute.
    const f32x4 z4 = {0.f, 0.f, 0.f, 0.f};
    for (int r = 0; r < QT; ++r){
        int2 br = bounds[q0 + r];
        float* row = attn + ((size_t)h * N_TOK + (q0 + r)) * N_TOK;
        f32x4* row4 = (f32x4*)row;
        int lo4 = br.x >> 2;                       // float4s fully before lo
        for (int p = tid; p < lo4; p += 256)
            __builtin_nontemporal_store(z4, &row4[p]);
        if (tid < (br.x & 3))                      // scalar remainder [lo4*4, lo)
            __builtin_nontemporal_store(0.f, &row[(lo4 << 2) + tid]);
        int hb = (br.y + 3) & ~3;                  // first aligned pos >= hi
        if (tid < hb - br.y)                       // scalar remainder [hi, hb)
            __builtin_nontemporal_store(0.f, &row[br.y + tid]);
        for (int p = (hb >> 2) + tid; p < N_TOK / 4; p += 256)
            __builtin_nontemporal_store(z4, &row4[p]);
    }
}

extern "C" void kernel_launch(void* const* d_in, const int* in_sizes, int n_in,
                              void* d_out, int out_size, void* d_ws, size_t ws_size,
                              hipStream_t stream)
{
    const float* x_q  = (const float*)d_in[0];
    const float* x_kv = (const float*)d_in[1];
    const void* batch_q  = d_in[2];
    const void* batch_kv = d_in[3];
    const float* Wq = (const float*)d_in[4];
    const float* bq = (const float*)d_in[5];
    const float* Wk = (const float*)d_in[6];
    const float* bk = (const float*)d_in[7];
    const float* Wv = (const float*)d_in[8];
    const float* bv = (const float*)d_in[9];
    const float* Wo = (const float*)d_in[10];
    const float* bo = (const float*)d_in[11];

    char* ws = (char*)d_ws;
    float* Q  = (float*)ws;                                 // 4 MB fp32
    u16*   Kp = (u16*)(ws + (size_t)4 * 1024 * 1024);       // 2 MB bf16, head-major
    u16*   Vp = (u16*)(ws + (size_t)6 * 1024 * 1024);       // 2 MB bf16, head-major
    float* O  = (float*)(ws + (size_t)8 * 1024 * 1024);     // 4 MB fp32
    int2* bounds = (int2*)(ws + (size_t)12 * 1024 * 1024);  // 32 KB

    float* out  = (float*)d_out;                            // [4096,256] fp32
    float* attn = out + (size_t)N_TOK * DM;                 // [8,4096,4096] fp32

    bounds_kernel<<<N_TOK / 256, 256, 0, stream>>>(batch_q, batch_kv, bounds);
    proj_kernel<0><<<N_TOK/8, 256, 0, stream>>>(x_q,  Wq, bq, Q);
    proj_kv_kernel<<<N_TOK/8, 256, 0, stream>>>(x_kv, Wk, bk, Wv, bv, Kp, Vp);
    attn_kernel<<<dim3(N_TOK / QT, NH), 256, 0, stream>>>(Q, Kp, Vp, bounds, attn, O);
    proj_kernel<0><<<N_TOK/8, 256, 0, stream>>>((const float*)O, Wo, bo, out);
}

// Round 4
// 699.318 us; speedup vs baseline: 1.1129x; 1.0649x over previous
//
#include <hip/hip_runtime.h>

#define N_TOK 4096
#define DM 256
#define NH 8
#define DK 32

using u16 = unsigned short;
using u32 = unsigned int;
using i64 = long long;
typedef float f32x4 __attribute__((ext_vector_type(4)));

__device__ __forceinline__ float bf2f(u16 u){ return __uint_as_float(((u32)u) << 16); }
__device__ __forceinline__ u16 f2bf(float f){
    u32 x = __float_as_uint(f);
    x += 0x7fffu + ((x >> 16) & 1u);
    return (u16)(x >> 16);
}

// ================= fused pre-kernel: projQ (b<512) | projKV (b<1024) | bounds =================
__global__ __launch_bounds__(256)
void pre_kernel(const float* __restrict__ xq, const float* __restrict__ xkv,
                const void* __restrict__ batch_q, const void* __restrict__ batch_kv,
                const float* __restrict__ Wq, const float* __restrict__ bq,
                const float* __restrict__ Wk, const float* __restrict__ bk,
                const float* __restrict__ Wv, const float* __restrict__ bv,
                float* __restrict__ Q, u16* __restrict__ Kp, u16* __restrict__ Vp,
                int2* __restrict__ bounds)
{
    const int b = blockIdx.x;
    const int c = threadIdx.x;
    const int ROWS = 8;

    if (b < 512){
        // ---- Q projection, fp32 token-major out ----
        int row0 = b * ROWS;
        float acc[ROWS];
        float bvv = bq[c];
#pragma unroll
        for (int r = 0; r < ROWS; ++r) acc[r] = bvv;
        const float4* Wv4 = (const float4*)(Wq + (size_t)c * DM);
        const float4* xb  = (const float4*)(xq + (size_t)row0 * DM);
        for (int i = 0; i < DM / 4; ++i){
            float4 w = Wv4[i];
#pragma unroll
            for (int r = 0; r < ROWS; ++r){
                float4 xv = xb[r * (DM / 4) + i];
                acc[r] += xv.x * w.x + xv.y * w.y + xv.z * w.z + xv.w * w.w;
            }
        }
#pragma unroll
        for (int r = 0; r < ROWS; ++r)
            Q[(size_t)(row0 + r) * DM + c] = acc[r];
    } else if (b < 1024){
        // ---- fused K+V projection, bf16 HEAD-MAJOR out [h][token][32] ----
        int row0 = (b - 512) * ROWS;
        int hh = c >> 5, dd = c & 31;
        float acck[ROWS], accv[ROWS];
        float bkv = bk[c], bvv = bv[c];
#pragma unroll
        for (int r = 0; r < ROWS; ++r){ acck[r] = bkv; accv[r] = bvv; }
        const float4* Wk4 = (const float4*)(Wk + (size_t)c * DM);
        const float4* Wv4 = (const float4*)(Wv + (size_t)c * DM);
        const float4* xb  = (const float4*)(xkv + (size_t)row0 * DM);
        for (int i = 0; i < DM / 4; ++i){
            float4 wk = Wk4[i];
            float4 wv = Wv4[i];
#pragma unroll
            for (int r = 0; r < ROWS; ++r){
                float4 xv = xb[r * (DM / 4) + i];
                acck[r] += xv.x * wk.x + xv.y * wk.y + xv.z * wk.z + xv.w * wk.w;
                accv[r] += xv.x * wv.x + xv.y * wv.y + xv.z * wv.z + xv.w * wv.w;
            }
        }
#pragma unroll
        for (int r = 0; r < ROWS; ++r){
            size_t idx = ((size_t)hh * N_TOK + (row0 + r)) * DK + dd;
            Kp[idx] = f2bf(acck[r]);
            Vp[idx] = f2bf(accv[r]);
        }
    } else {
        // ---- segment bounds (batch sorted; int32 or int64 probed) ----
        int q = (b - 1024) * 256 + c;
        const int* kv32 = (const int*)batch_kv;
        const i64* kv64 = (const i64*)batch_kv;
        bool is64 = (kv32[N_TOK - 1] == 0);
        int s = is64 ? (int)((const i64*)batch_q)[q] : ((const int*)batch_q)[q];
        int lo = 0, hi = N_TOK;
        while (lo < hi){ int m = (lo + hi) >> 1; int v = is64 ? (int)kv64[m] : kv32[m]; if (v < s) lo = m + 1; else hi = m; }
        int lo2 = lo, hi2 = N_TOK;
        while (lo2 < hi2){ int m = (lo2 + hi2) >> 1; int v = is64 ? (int)kv64[m] : kv32[m]; if (v <= s) lo2 = m + 1; else hi2 = m; }
        bounds[q] = make_int2(lo, lo2);
    }
}

// out[r][c] = sum_d x[r][d] * W[c][d] + b[c]   (output projection)
__global__ __launch_bounds__(256)
void proj_kernel(const float* __restrict__ x, const float* __restrict__ W,
                 const float* __restrict__ bias, float* __restrict__ out)
{
    const int ROWS = 8;
    int row0 = blockIdx.x * ROWS;
    int c = threadIdx.x;
    float acc[ROWS];
    float bv = bias[c];
#pragma unroll
    for (int r = 0; r < ROWS; ++r) acc[r] = bv;
    const float4* Wv = (const float4*)(W + (size_t)c * DM);
    const float4* xb = (const float4*)(x + (size_t)row0 * DM);
    for (int i = 0; i < DM / 4; ++i){
        float4 w = Wv[i];
#pragma unroll
        for (int r = 0; r < ROWS; ++r){
            float4 xv = xb[r * (DM / 4) + i];
            acc[r] += xv.x * w.x + xv.y * w.y + xv.z * w.z + xv.w * w.w;
        }
    }
#pragma unroll
    for (int r = 0; r < ROWS; ++r)
        out[(size_t)(row0 + r) * DM + c] = acc[r];
}

// R0 chassis: one block per (query q, head h), 32768 blocks, head-major K/V.
// Only change vs the 703us baseline: the full-row store is issued BEFORE the
// PV loop (both only read sc[] after the sum-reduce barrier), so the NT-store
// drain overlaps PV's V-loads and FMAs instead of serializing after them.
__global__ __launch_bounds__(256)
void attn_kernel(const float* __restrict__ Q, const u16* __restrict__ K,
                 const u16* __restrict__ V, const int2* __restrict__ bounds,
                 float* __restrict__ attn, float* __restrict__ O)
{
    __shared__ float sc[N_TOK];    // unnormalized probs
    __shared__ float qs[DK];
    __shared__ float red[8];
    __shared__ float Osh[DK];

    int q = blockIdx.x, h = blockIdx.y, tid = threadIdx.x;
    int2 bnd = bounds[q];
    const int lo = bnd.x, hi = bnd.y;
    const u16* Kh = K + (size_t)h * N_TOK * DK;
    const u16* Vh = V + (size_t)h * N_TOK * DK;

    if (tid < DK){ qs[tid] = Q[(size_t)q * DM + h * DK + tid]; Osh[tid] = 0.f; }
    __syncthreads();

    const float scale = 0.17677669529663687f;   // 1/sqrt(32)

    // ---- scores + local max ----
    float lmax = -1e30f;
    for (int k = lo + tid; k < hi; k += 256){
        const uint4* kr = (const uint4*)(Kh + (size_t)k * DK);   // 64B dense
        float dot = 0.f;
#pragma unroll
        for (int i = 0; i < 4; ++i){
            uint4 p = kr[i];
            dot += qs[i*8+0]*bf2f((u16)p.x) + qs[i*8+1]*bf2f((u16)(p.x>>16));
            dot += qs[i*8+2]*bf2f((u16)p.y) + qs[i*8+3]*bf2f((u16)(p.y>>16));
            dot += qs[i*8+4]*bf2f((u16)p.z) + qs[i*8+5]*bf2f((u16)(p.z>>16));
            dot += qs[i*8+6]*bf2f((u16)p.w) + qs[i*8+7]*bf2f((u16)(p.w>>16));
        }
        dot *= scale;
        sc[k - lo] = dot;
        lmax = fmaxf(lmax, dot);
    }
#pragma unroll
    for (int off = 32; off; off >>= 1) lmax = fmaxf(lmax, __shfl_xor(lmax, off, 64));
    if ((tid & 63) == 0) red[tid >> 6] = lmax;
    __syncthreads();
    float m = fmaxf(fmaxf(red[0], red[1]), fmaxf(red[2], red[3]));

    // ---- exp + local sum ----
    float lsum = 0.f;
    for (int k = lo + tid; k < hi; k += 256){
        float p = __expf(sc[k - lo] - m);
        sc[k - lo] = p;
        lsum += p;
    }
#pragma unroll
    for (int off = 32; off; off >>= 1) lsum += __shfl_xor(lsum, off, 64);
    if ((tid & 63) == 0) red[4 + (tid >> 6)] = lsum;
    __syncthreads();
    float sum = red[4] + red[5] + red[6] + red[7];
    float inv = (sum > 0.f) ? (1.0f / sum) : 0.f;

    // ---- full attn row first (stores issue, drain overlaps PV below) ----
    f32x4* arow4 = (f32x4*)(attn + ((size_t)h * N_TOK + q) * N_TOK);
#pragma unroll
    for (int i = 0; i < N_TOK / 1024; ++i){
        int t = i * 256 + tid;
        int k0 = 4 * t;
        f32x4 w;
        w.x = (k0 + 0 >= lo && k0 + 0 < hi) ? sc[k0 + 0 - lo] * inv : 0.f;
        w.y = (k0 + 1 >= lo && k0 + 1 < hi) ? sc[k0 + 1 - lo] * inv : 0.f;
        w.z = (k0 + 2 >= lo && k0 + 2 < hi) ? sc[k0 + 2 - lo] * inv : 0.f;
        w.w = (k0 + 3 >= lo && k0 + 3 < hi) ? sc[k0 + 3 - lo] * inv : 0.f;
        __builtin_nontemporal_store(w, &arow4[t]);
    }

    // ---- PV ----
    int d2 = tid & 15;
    int g  = tid >> 4;
    float p0 = 0.f, p1 = 0.f;
    for (int k = lo + g; k < hi; k += 16){
        u32 pv = *(const u32*)(Vh + (size_t)k * DK + 2 * d2);    // dense 64B/k
        float p = sc[k - lo];
        p0 += p * bf2f((u16)pv);
        p1 += p * bf2f((u16)(pv >> 16));
    }
    p0 += __shfl_xor(p0, 16, 64); p0 += __shfl_xor(p0, 32, 64);
    p1 += __shfl_xor(p1, 16, 64); p1 += __shfl_xor(p1, 32, 64);
    if ((tid & 63) < 16){
        atomicAdd(&Osh[2 * d2 + 0], p0);
        atomicAdd(&Osh[2 * d2 + 1], p1);
    }

    __syncthreads();
    if (tid < DK) O[(size_t)q * DM + h * DK + tid] = Osh[tid] * inv;
}

extern "C" void kernel_launch(void* const* d_in, const int* in_sizes, int n_in,
                              void* d_out, int out_size, void* d_ws, size_t ws_size,
                              hipStream_t stream)
{
    const float* x_q  = (const float*)d_in[0];
    const float* x_kv = (const float*)d_in[1];
    const void* batch_q  = d_in[2];
    const void* batch_kv = d_in[3];
    const float* Wq = (const float*)d_in[4];
    const float* bq = (const float*)d_in[5];
    const float* Wk = (const float*)d_in[6];
    const float* bk = (const float*)d_in[7];
    const float* Wv = (const float*)d_in[8];
    const float* bv = (const float*)d_in[9];
    const float* Wo = (const float*)d_in[10];
    const float* bo = (const float*)d_in[11];

    char* ws = (char*)d_ws;
    float* Q  = (float*)ws;                                 // 4 MB fp32
    u16*   Kp = (u16*)(ws + (size_t)4 * 1024 * 1024);       // 2 MB bf16, head-major
    u16*   Vp = (u16*)(ws + (size_t)6 * 1024 * 1024);       // 2 MB bf16, head-major
    float* O  = (float*)(ws + (size_t)8 * 1024 * 1024);     // 4 MB fp32
    int2* bounds = (int2*)(ws + (size_t)12 * 1024 * 1024);  // 32 KB

    float* out  = (float*)d_out;                            // [4096,256] fp32
    float* attn = out + (size_t)N_TOK * DM;                 // [8,4096,4096] fp32

    // fused: projQ (512 blocks) | projKV (512) | bounds (16)
    pre_kernel<<<1040, 256, 0, stream>>>(x_q, x_kv, batch_q, batch_kv,
                                         Wq, bq, Wk, bk, Wv, bv,
                                         Q, Kp, Vp, bounds);
    attn_kernel<<<dim3(N_TOK, NH), 256, 0, stream>>>(Q, Kp, Vp, bounds, attn, O);
    proj_kernel<<<N_TOK/8, 256, 0, stream>>>((const float*)O, Wo, bo, out);
}

// Round 5
// 673.908 us; speedup vs baseline: 1.1549x; 1.0377x over previous
//
#include <hip/hip_runtime.h>

#define N_TOK 4096
#define DM 256
#define NH 8
#define DK 32

using u16 = unsigned short;
using u32 = unsigned int;
using i64 = long long;
typedef float f32x4 __attribute__((ext_vector_type(4)));

__device__ __forceinline__ float bf2f(u16 u){ return __uint_as_float(((u32)u) << 16); }
__device__ __forceinline__ u16 f2bf(float f){
    u32 x = __float_as_uint(f);
    x += 0x7fffu + ((x >> 16) & 1u);
    return (u16)(x >> 16);
}

// ===== wt_kernel: transpose W[256][256] -> WTb where WTb4[d4*256 + c] = {W[c][4d4..4d4+3]}
// Blocks 0..63: 4 matrices x 16 blocks each. Blocks 64..79: segment bounds.
// After this, every proj load of W is fully coalesced (consecutive lanes ->
// consecutive 16B), replacing the 64-lines-per-instruction scatter of W[c][:].
__global__ __launch_bounds__(256)
void wt_kernel(const float* __restrict__ Wq, const float* __restrict__ Wk,
               const float* __restrict__ Wv, const float* __restrict__ Wo,
               float* __restrict__ Tq, float* __restrict__ Tk,
               float* __restrict__ Tv, float* __restrict__ To,
               const void* __restrict__ batch_q, const void* __restrict__ batch_kv,
               int2* __restrict__ bounds)
{
    const int b = blockIdx.x;
    const int t = threadIdx.x;
    if (b < 64){
        const float* W = (b < 16) ? Wq : (b < 32) ? Wk : (b < 48) ? Wv : Wo;
        float*      T  = (b < 16) ? Tq : (b < 32) ? Tk : (b < 48) ? Tv : To;
        int blk = b & 15;                       // 16 blocks per matrix
        float4* T4 = (float4*)T;
#pragma unroll
        for (int f = 0; f < 4; ++f){
            int F = blk * 1024 + f * 256 + t;   // float4 index; coalesced writes
            int d4 = F >> 8;                    // 0..63
            int c  = F & 255;                   // 0..255
            // 16B-aligned contiguous read of W[c][4d4..4d4+3]
            float4 v = *(const float4*)(W + (size_t)c * DM + 4 * d4);
            T4[F] = v;
        }
    } else {
        // ---- segment bounds (batch sorted; int32 or int64 probed) ----
        int q = (b - 64) * 256 + t;
        const int* kv32 = (const int*)batch_kv;
        const i64* kv64 = (const i64*)batch_kv;
        bool is64 = (kv32[N_TOK - 1] == 0);
        int s = is64 ? (int)((const i64*)batch_q)[q] : ((const int*)batch_q)[q];
        int lo = 0, hi = N_TOK;
        while (lo < hi){ int m = (lo + hi) >> 1; int v = is64 ? (int)kv64[m] : kv32[m]; if (v < s) lo = m + 1; else hi = m; }
        int lo2 = lo, hi2 = N_TOK;
        while (lo2 < hi2){ int m = (lo2 + hi2) >> 1; int v = is64 ? (int)kv64[m] : kv32[m]; if (v <= s) lo2 = m + 1; else hi2 = m; }
        bounds[q] = make_int2(lo, lo2);
    }
}

// ================= fused pre-kernel: projQ (b<512) | projKV (b<1024) =================
// Reads transposed W: w = WT4[i*256 + c]  (coalesced; identical float4 values
// to the old (W + c*DM) layout -> bit-identical arithmetic).
__global__ __launch_bounds__(256)
void pre_kernel(const float* __restrict__ xq, const float* __restrict__ xkv,
                const float* __restrict__ Tq, const float* __restrict__ bq,
                const float* __restrict__ Tk, const float* __restrict__ bk,
                const float* __restrict__ Tv, const float* __restrict__ bv,
                float* __restrict__ Q, u16* __restrict__ Kp, u16* __restrict__ Vp)
{
    const int b = blockIdx.x;
    const int c = threadIdx.x;
    const int ROWS = 8;

    if (b < 512){
        // ---- Q projection, fp32 token-major out ----
        int row0 = b * ROWS;
        float acc[ROWS];
        float bvv = bq[c];
#pragma unroll
        for (int r = 0; r < ROWS; ++r) acc[r] = bvv;
        const float4* T4 = (const float4*)Tq;
        const float4* xb = (const float4*)(xq + (size_t)row0 * DM);
        for (int i = 0; i < DM / 4; ++i){
            float4 w = T4[i * 256 + c];
#pragma unroll
            for (int r = 0; r < ROWS; ++r){
                float4 xv = xb[r * (DM / 4) + i];
                acc[r] += xv.x * w.x + xv.y * w.y + xv.z * w.z + xv.w * w.w;
            }
        }
#pragma unroll
        for (int r = 0; r < ROWS; ++r)
            Q[(size_t)(row0 + r) * DM + c] = acc[r];
    } else {
        // ---- fused K+V projection, bf16 HEAD-MAJOR out [h][token][32] ----
        int row0 = (b - 512) * ROWS;
        int hh = c >> 5, dd = c & 31;
        float acck[ROWS], accv[ROWS];
        float bkv = bk[c], bvv = bv[c];
#pragma unroll
        for (int r = 0; r < ROWS; ++r){ acck[r] = bkv; accv[r] = bvv; }
        const float4* Tk4 = (const float4*)Tk;
        const float4* Tv4 = (const float4*)Tv;
        const float4* xb  = (const float4*)(xkv + (size_t)row0 * DM);
        for (int i = 0; i < DM / 4; ++i){
            float4 wk = Tk4[i * 256 + c];
            float4 wv = Tv4[i * 256 + c];
#pragma unroll
            for (int r = 0; r < ROWS; ++r){
                float4 xv = xb[r * (DM / 4) + i];
                acck[r] += xv.x * wk.x + xv.y * wk.y + xv.z * wk.z + xv.w * wk.w;
                accv[r] += xv.x * wv.x + xv.y * wv.y + xv.z * wv.z + xv.w * wv.w;
            }
        }
#pragma unroll
        for (int r = 0; r < ROWS; ++r){
            size_t idx = ((size_t)hh * N_TOK + (row0 + r)) * DK + dd;
            Kp[idx] = f2bf(acck[r]);
            Vp[idx] = f2bf(accv[r]);
        }
    }
}

// out[r][c] = sum_d x[r][d] * W[c][d] + b[c]   (output projection, transposed W)
__global__ __launch_bounds__(256)
void proj_kernel(const float* __restrict__ x, const float* __restrict__ T,
                 const float* __restrict__ bias, float* __restrict__ out)
{
    const int ROWS = 8;
    int row0 = blockIdx.x * ROWS;
    int c = threadIdx.x;
    float acc[ROWS];
    float bv = bias[c];
#pragma unroll
    for (int r = 0; r < ROWS; ++r) acc[r] = bv;
    const float4* T4 = (const float4*)T;
    const float4* xb = (const float4*)(x + (size_t)row0 * DM);
    for (int i = 0; i < DM / 4; ++i){
        float4 w = T4[i * 256 + c];
#pragma unroll
        for (int r = 0; r < ROWS; ++r){
            float4 xv = xb[r * (DM / 4) + i];
            acc[r] += xv.x * w.x + xv.y * w.y + xv.z * w.z + xv.w * w.w;
        }
    }
#pragma unroll
    for (int r = 0; r < ROWS; ++r)
        out[(size_t)(row0 + r) * DM + c] = acc[r];
}

// R4 chassis (unchanged, byte-for-byte): one block per (query q, head h).
__global__ __launch_bounds__(256)
void attn_kernel(const float* __restrict__ Q, const u16* __restrict__ K,
                 const u16* __restrict__ V, const int2* __restrict__ bounds,
                 float* __restrict__ attn, float* __restrict__ O)
{
    __shared__ float sc[N_TOK];    // unnormalized probs
    __shared__ float qs[DK];
    __shared__ float red[8];
    __shared__ float Osh[DK];

    int q = blockIdx.x, h = blockIdx.y, tid = threadIdx.x;
    int2 bnd = bounds[q];
    const int lo = bnd.x, hi = bnd.y;
    const u16* Kh = K + (size_t)h * N_TOK * DK;
    const u16* Vh = V + (size_t)h * N_TOK * DK;

    if (tid < DK){ qs[tid] = Q[(size_t)q * DM + h * DK + tid]; Osh[tid] = 0.f; }
    __syncthreads();

    const float scale = 0.17677669529663687f;   // 1/sqrt(32)

    // ---- scores + local max ----
    float lmax = -1e30f;
    for (int k = lo + tid; k < hi; k += 256){
        const uint4* kr = (const uint4*)(Kh + (size_t)k * DK);   // 64B dense
        float dot = 0.f;
#pragma unroll
        for (int i = 0; i < 4; ++i){
            uint4 p = kr[i];
            dot += qs[i*8+0]*bf2f((u16)p.x) + qs[i*8+1]*bf2f((u16)(p.x>>16));
            dot += qs[i*8+2]*bf2f((u16)p.y) + qs[i*8+3]*bf2f((u16)(p.y>>16));
            dot += qs[i*8+4]*bf2f((u16)p.z) + qs[i*8+5]*bf2f((u16)(p.z>>16));
            dot += qs[i*8+6]*bf2f((u16)p.w) + qs[i*8+7]*bf2f((u16)(p.w>>16));
        }
        dot *= scale;
        sc[k - lo] = dot;
        lmax = fmaxf(lmax, dot);
    }
#pragma unroll
    for (int off = 32; off; off >>= 1) lmax = fmaxf(lmax, __shfl_xor(lmax, off, 64));
    if ((tid & 63) == 0) red[tid >> 6] = lmax;
    __syncthreads();
    float m = fmaxf(fmaxf(red[0], red[1]), fmaxf(red[2], red[3]));

    // ---- exp + local sum ----
    float lsum = 0.f;
    for (int k = lo + tid; k < hi; k += 256){
        float p = __expf(sc[k - lo] - m);
        sc[k - lo] = p;
        lsum += p;
    }
#pragma unroll
    for (int off = 32; off; off >>= 1) lsum += __shfl_xor(lsum, off, 64);
    if ((tid & 63) == 0) red[4 + (tid >> 6)] = lsum;
    __syncthreads();
    float sum = red[4] + red[5] + red[6] + red[7];
    float inv = (sum > 0.f) ? (1.0f / sum) : 0.f;

    // ---- full attn row first (stores issue, drain overlaps PV below) ----
    f32x4* arow4 = (f32x4*)(attn + ((size_t)h * N_TOK + q) * N_TOK);
#pragma unroll
    for (int i = 0; i < N_TOK / 1024; ++i){
        int t = i * 256 + tid;
        int k0 = 4 * t;
        f32x4 w;
        w.x = (k0 + 0 >= lo && k0 + 0 < hi) ? sc[k0 + 0 - lo] * inv : 0.f;
        w.y = (k0 + 1 >= lo && k0 + 1 < hi) ? sc[k0 + 1 - lo] * inv : 0.f;
        w.z = (k0 + 2 >= lo && k0 + 2 < hi) ? sc[k0 + 2 - lo] * inv : 0.f;
        w.w = (k0 + 3 >= lo && k0 + 3 < hi) ? sc[k0 + 3 - lo] * inv : 0.f;
        __builtin_nontemporal_store(w, &arow4[t]);
    }

    // ---- PV ----
    int d2 = tid & 15;
    int g  = tid >> 4;
    float p0 = 0.f, p1 = 0.f;
    for (int k = lo + g; k < hi; k += 16){
        u32 pv = *(const u32*)(Vh + (size_t)k * DK + 2 * d2);    // dense 64B/k
        float p = sc[k - lo];
        p0 += p * bf2f((u16)pv);
        p1 += p * bf2f((u16)(pv >> 16));
    }
    p0 += __shfl_xor(p0, 16, 64); p0 += __shfl_xor(p0, 32, 64);
    p1 += __shfl_xor(p1, 16, 64); p1 += __shfl_xor(p1, 32, 64);
    if ((tid & 63) < 16){
        atomicAdd(&Osh[2 * d2 + 0], p0);
        atomicAdd(&Osh[2 * d2 + 1], p1);
    }

    __syncthreads();
    if (tid < DK) O[(size_t)q * DM + h * DK + tid] = Osh[tid] * inv;
}

extern "C" void kernel_launch(void* const* d_in, const int* in_sizes, int n_in,
                              void* d_out, int out_size, void* d_ws, size_t ws_size,
                              hipStream_t stream)
{
    const float* x_q  = (const float*)d_in[0];
    const float* x_kv = (const float*)d_in[1];
    const void* batch_q  = d_in[2];
    const void* batch_kv = d_in[3];
    const float* Wq = (const float*)d_in[4];
    const float* bq = (const float*)d_in[5];
    const float* Wk = (const float*)d_in[6];
    const float* bk = (const float*)d_in[7];
    const float* Wv = (const float*)d_in[8];
    const float* bv = (const float*)d_in[9];
    const float* Wo = (const float*)d_in[10];
    const float* bo = (const float*)d_in[11];

    char* ws = (char*)d_ws;
    float* Q  = (float*)ws;                                 // 4 MB fp32
    u16*   Kp = (u16*)(ws + (size_t)4 * 1024 * 1024);       // 2 MB bf16, head-major
    u16*   Vp = (u16*)(ws + (size_t)6 * 1024 * 1024);       // 2 MB bf16, head-major
    float* O  = (float*)(ws + (size_t)8 * 1024 * 1024);     // 4 MB fp32
    int2* bounds = (int2*)(ws + (size_t)12 * 1024 * 1024);  // 32 KB
    float* Tq = (float*)(ws + (size_t)13 * 1024 * 1024);    // 256 KB each
    float* Tk = (float*)(ws + (size_t)13 * 1024 * 1024 + 256 * 1024);
    float* Tv = (float*)(ws + (size_t)13 * 1024 * 1024 + 512 * 1024);
    float* To = (float*)(ws + (size_t)13 * 1024 * 1024 + 768 * 1024);

    float* out  = (float*)d_out;                            // [4096,256] fp32
    float* attn = out + (size_t)N_TOK * DM;                 // [8,4096,4096] fp32

    // transpose the 4 weight matrices (64 blocks) + bounds (16 blocks)
    wt_kernel<<<80, 256, 0, stream>>>(Wq, Wk, Wv, Wo, Tq, Tk, Tv, To,
                                      batch_q, batch_kv, bounds);
    // fused: projQ (512 blocks) | projKV (512)
    pre_kernel<<<1024, 256, 0, stream>>>(x_q, x_kv, Tq, bq, Tk, bk, Tv, bv,
                                         Q, Kp, Vp);
    attn_kernel<<<dim3(N_TOK, NH), 256, 0, stream>>>(Q, Kp, Vp, bounds, attn, O);
    proj_kernel<<<N_TOK/8, 256, 0, stream>>>((const float*)O, To, bo, out);
}